// Round 1
// baseline (771.310 us; speedup 1.0000x reference)
//
#include <hip/hip_runtime.h>
#include <math.h>

// ---------------- GEMM1: h1[N,64] = x[N,128] @ W1[128,64] ----------------
__global__ __launch_bounds__(256) void k_gemm1(const float* __restrict__ x,
                                               const float* __restrict__ W1,
                                               float* __restrict__ h1, int N) {
    __shared__ float sB[128 * 64];  // 32 KB, full W1
    __shared__ float sA[64 * 68];   // 17.4 KB, 64 rows x 64 k-cols, stride 68
    const int t = threadIdx.x;
    const int n0 = blockIdx.x * 64;
    {   // stage full W1 (2048 float4)
        const float4* w4 = (const float4*)W1;
        float4* s4 = (float4*)sB;
#pragma unroll
        for (int i = 0; i < 8; ++i) s4[t + i * 256] = w4[t + i * 256];
    }
    const int r0 = (t >> 3) * 2;
    const int c0 = (t & 7) * 8;
    float acc0[8] = {0, 0, 0, 0, 0, 0, 0, 0};
    float acc1[8] = {0, 0, 0, 0, 0, 0, 0, 0};
    for (int kb = 0; kb < 2; ++kb) {
        __syncthreads();
        // stage 64x64 chunk of x (1024 float4)
#pragma unroll
        for (int i = 0; i < 4; ++i) {
            int idx = t + i * 256;
            int r = idx >> 4, kc = idx & 15;
            int n = n0 + r;
            float4 v = make_float4(0.f, 0.f, 0.f, 0.f);
            if (n < N) v = ((const float4*)x)[(size_t)n * 32 + kb * 16 + kc];
            *(float4*)&sA[r * 68 + kc * 4] = v;
        }
        __syncthreads();
        const float* bptr = &sB[kb * 64 * 64];
#pragma unroll 8
        for (int kk = 0; kk < 64; ++kk) {
            float a0 = sA[r0 * 68 + kk];
            float a1 = sA[(r0 + 1) * 68 + kk];
            const float* bp = &bptr[kk * 64 + c0];
            float4 b0 = *(const float4*)bp;
            float4 b1v = *(const float4*)(bp + 4);
            acc0[0] += a0 * b0.x; acc0[1] += a0 * b0.y; acc0[2] += a0 * b0.z; acc0[3] += a0 * b0.w;
            acc0[4] += a0 * b1v.x; acc0[5] += a0 * b1v.y; acc0[6] += a0 * b1v.z; acc0[7] += a0 * b1v.w;
            acc1[0] += a1 * b0.x; acc1[1] += a1 * b0.y; acc1[2] += a1 * b0.z; acc1[3] += a1 * b0.w;
            acc1[4] += a1 * b1v.x; acc1[5] += a1 * b1v.y; acc1[6] += a1 * b1v.z; acc1[7] += a1 * b1v.w;
        }
    }
    int n = n0 + r0;
    if (n < N) {
        *(float4*)&h1[(size_t)n * 64 + c0] = make_float4(acc0[0], acc0[1], acc0[2], acc0[3]);
        *(float4*)&h1[(size_t)n * 64 + c0 + 4] = make_float4(acc0[4], acc0[5], acc0[6], acc0[7]);
    }
    if (n + 1 < N) {
        *(float4*)&h1[(size_t)(n + 1) * 64 + c0] = make_float4(acc1[0], acc1[1], acc1[2], acc1[3]);
        *(float4*)&h1[(size_t)(n + 1) * 64 + c0 + 4] = make_float4(acc1[4], acc1[5], acc1[6], acc1[7]);
    }
}

// ------------- GEMM2: h2[N,128] = relu(x1pre+b1) @ W2[64,128] -------------
__global__ __launch_bounds__(256) void k_gemm2(const float* __restrict__ x1pre,
                                               const float* __restrict__ W2,
                                               const float* __restrict__ b1,
                                               float* __restrict__ h2, int N) {
    __shared__ float sB[64 * 128];  // 32 KB, full W2
    __shared__ float sA[64 * 68];
    const int t = threadIdx.x;
    const int n0 = blockIdx.x * 64;
    {
        const float4* w4 = (const float4*)W2;
        float4* s4 = (float4*)sB;
#pragma unroll
        for (int i = 0; i < 8; ++i) s4[t + i * 256] = w4[t + i * 256];
    }
#pragma unroll
    for (int i = 0; i < 4; ++i) {
        int idx = t + i * 256;
        int r = idx >> 4, kc = idx & 15;
        int n = n0 + r;
        float4 v = make_float4(0.f, 0.f, 0.f, 0.f);
        if (n < N) {
            v = ((const float4*)x1pre)[(size_t)n * 16 + kc];
            float4 bb = ((const float4*)b1)[kc];
            v.x = fmaxf(v.x + bb.x, 0.f);
            v.y = fmaxf(v.y + bb.y, 0.f);
            v.z = fmaxf(v.z + bb.z, 0.f);
            v.w = fmaxf(v.w + bb.w, 0.f);
        }
        *(float4*)&sA[r * 68 + kc * 4] = v;
    }
    __syncthreads();
    const int r0 = (t >> 3) * 2;
    const int cb = (t & 7) * 4;  // cols: cb + 32*j + i
    float acc0[16], acc1[16];
#pragma unroll
    for (int i = 0; i < 16; ++i) { acc0[i] = 0.f; acc1[i] = 0.f; }
#pragma unroll 4
    for (int k = 0; k < 64; ++k) {
        float a0 = sA[r0 * 68 + k];
        float a1 = sA[(r0 + 1) * 68 + k];
#pragma unroll
        for (int j = 0; j < 4; ++j) {
            float4 b = *(const float4*)&sB[k * 128 + cb + 32 * j];
            acc0[j * 4 + 0] += a0 * b.x; acc0[j * 4 + 1] += a0 * b.y;
            acc0[j * 4 + 2] += a0 * b.z; acc0[j * 4 + 3] += a0 * b.w;
            acc1[j * 4 + 0] += a1 * b.x; acc1[j * 4 + 1] += a1 * b.y;
            acc1[j * 4 + 2] += a1 * b.z; acc1[j * 4 + 3] += a1 * b.w;
        }
    }
    int n = n0 + r0;
    if (n < N) {
#pragma unroll
        for (int j = 0; j < 4; ++j)
            *(float4*)&h2[(size_t)n * 128 + cb + 32 * j] =
                make_float4(acc0[j * 4 + 0], acc0[j * 4 + 1], acc0[j * 4 + 2], acc0[j * 4 + 3]);
    }
    if (n + 1 < N) {
#pragma unroll
        for (int j = 0; j < 4; ++j)
            *(float4*)&h2[(size_t)(n + 1) * 128 + cb + 32 * j] =
                make_float4(acc1[j * 4 + 0], acc1[j * 4 + 1], acc1[j * 4 + 2], acc1[j * 4 + 3]);
    }
}

// --------- attention coefficients, layer 1: al[n,h] = sum_c h1[n,h,c]*a[h,c] ---------
__global__ __launch_bounds__(256) void k_al1(const float* __restrict__ h1,
                                             const float* __restrict__ as1,
                                             const float* __restrict__ ad1,
                                             float* __restrict__ al1s,
                                             float* __restrict__ al1d, int N) {
    int node = blockIdx.x * 4 + (threadIdx.x >> 6);
    if (node >= N) return;
    int c = threadIdx.x & 63;
    float v = h1[(size_t)node * 64 + c];
    float ps = v * as1[c];
    float pd = v * ad1[c];
    ps += __shfl_xor(ps, 1); ps += __shfl_xor(ps, 2); ps += __shfl_xor(ps, 4);
    pd += __shfl_xor(pd, 1); pd += __shfl_xor(pd, 2); pd += __shfl_xor(pd, 4);
    if ((c & 7) == 0) {
        al1s[(size_t)node * 8 + (c >> 3)] = ps;
        al1d[(size_t)node * 8 + (c >> 3)] = pd;
    }
}

// --------- attention coefficients, layer 2 (H=1, C=128) ---------
__global__ __launch_bounds__(256) void k_al2(const float* __restrict__ h2,
                                             const float* __restrict__ as2,
                                             const float* __restrict__ ad2,
                                             float* __restrict__ al2s,
                                             float* __restrict__ al2d, int N) {
    int node = blockIdx.x * 4 + (threadIdx.x >> 6);
    if (node >= N) return;
    int c = threadIdx.x & 63;
    float2 v = ((const float2*)h2)[(size_t)node * 64 + c];
    float ps = v.x * as2[2 * c] + v.y * as2[2 * c + 1];
    float pd = v.x * ad2[2 * c] + v.y * ad2[2 * c + 1];
#pragma unroll
    for (int off = 1; off < 64; off <<= 1) {
        ps += __shfl_xor(ps, off);
        pd += __shfl_xor(pd, off);
    }
    if (c == 0) { al2s[node] = ps; al2d[node] = pd; }
}

// ---------------- CSR construction ----------------
__global__ void k_deg(const int* __restrict__ dst, int* __restrict__ deg, int E) {
    int e = blockIdx.x * 256 + threadIdx.x;
    if (e < E) atomicAdd(&deg[dst[e]], 1);
}

__global__ void k_scan1(const int* __restrict__ deg, int* __restrict__ row_ptr,
                        int* __restrict__ bsums, int N) {
    __shared__ int sh[256];
    int t = threadIdx.x, b = blockIdx.x;
    int i = b * 256 + t;
    int v = (i < N) ? (deg[i] + 1) : 0;  // +1 for self-loop
    sh[t] = v;
    __syncthreads();
    int accv = v;
    for (int off = 1; off < 256; off <<= 1) {
        int u = (t >= off) ? sh[t - off] : 0;
        __syncthreads();
        accv += u;
        sh[t] = accv;
        __syncthreads();
    }
    if (i < N) row_ptr[i] = accv - v;  // exclusive
    if (t == 255) bsums[b] = accv;     // block total
}

__global__ void k_scan2(int* __restrict__ bsums, int nb) {
    __shared__ int sh[512];
    int t = threadIdx.x;
    int v = (t < nb) ? bsums[t] : 0;
    sh[t] = v;
    __syncthreads();
    int accv = v;
    for (int off = 1; off < 512; off <<= 1) {
        int u = (t >= off) ? sh[t - off] : 0;
        __syncthreads();
        accv += u;
        sh[t] = accv;
        __syncthreads();
    }
    if (t < nb) bsums[t] = accv - v;  // exclusive block offsets
}

__global__ void k_scan3(int* __restrict__ row_ptr, const int* __restrict__ bsums,
                        int N, int total) {
    int i = blockIdx.x * 256 + threadIdx.x;
    if (i < N) row_ptr[i] += bsums[blockIdx.x];
    if (i == 0) row_ptr[N] = total;
}

__global__ void k_fill(const int* __restrict__ src, const int* __restrict__ dst,
                       const int* __restrict__ row_ptr, int* __restrict__ fill,
                       int* __restrict__ col, int E, int N) {
    int i = blockIdx.x * 256 + threadIdx.x;
    if (i < E) {
        int d = dst[i];
        int pos = row_ptr[d] + atomicAdd(&fill[d], 1);
        col[pos] = src[i];
    } else if (i < E + N) {
        int n = i - E;
        int pos = row_ptr[n] + atomicAdd(&fill[n], 1);
        col[pos] = n;  // self-loop
    }
}

// ---------------- edge aggregation, layer 1: wave per dst node ----------------
// x1pre[n,c] = sum_e w_e * h1[src_e, c] / sum_e w_e   (fused softmax)
__global__ __launch_bounds__(256) void k_edge1(const float* __restrict__ h1,
                                               const float* __restrict__ al1s,
                                               const float* __restrict__ al1d,
                                               const int* __restrict__ row_ptr,
                                               const int* __restrict__ col,
                                               float* __restrict__ x1pre, int N) {
    int node = blockIdx.x * 4 + (threadIdx.x >> 6);
    if (node >= N) return;
    int c = threadIdx.x & 63;
    int h = c >> 3;
    float a_d = al1d[(size_t)node * 8 + h];
    int s0 = row_ptr[node], s1 = row_ptr[node + 1];
    float den = 0.f, acc = 0.f;
    for (int s = s0; s < s1; ++s) {
        int src = col[s];
        float e = al1s[(size_t)src * 8 + h] + a_d;
        e = (e > 0.f) ? e : 0.2f * e;
        float w = __expf(e);
        den += w;
        acc += w * h1[(size_t)src * 64 + c];
    }
    x1pre[(size_t)node * 64 + c] = acc / den;
}

// ---------------- edge aggregation, layer 2: wave per dst node, 2 feats/lane ----------------
__global__ __launch_bounds__(256) void k_edge2(const float* __restrict__ h2,
                                               const float* __restrict__ al2s,
                                               const float* __restrict__ al2d,
                                               const int* __restrict__ row_ptr,
                                               const int* __restrict__ col,
                                               const float* __restrict__ b2,
                                               float* __restrict__ x2, int N) {
    int node = blockIdx.x * 4 + (threadIdx.x >> 6);
    if (node >= N) return;
    int c = threadIdx.x & 63;
    float a_d = al2d[node];
    int s0 = row_ptr[node], s1 = row_ptr[node + 1];
    float accx = 0.f, accy = 0.f, den = 0.f;
    const float2* h22 = (const float2*)h2;
    for (int s = s0; s < s1; ++s) {
        int src = col[s];
        float e = al2s[src] + a_d;
        e = (e > 0.f) ? e : 0.2f * e;
        float w = __expf(e);
        den += w;
        float2 hv = h22[(size_t)src * 64 + c];
        accx += w * hv.x;
        accy += w * hv.y;
    }
    float invd = 1.f / den;
    float2 ob = ((const float2*)b2)[c];
    float2 r;
    r.x = accx * invd + ob.x;
    r.y = accy * invd + ob.y;
    ((float2*)x2)[(size_t)node * 64 + c] = r;
}

// ---------------- mean pool over sorted batch (run-length chunked atomics) ----------------
__global__ __launch_bounds__(128) void k_pool(const float* __restrict__ x2,
                                              const int* __restrict__ batch,
                                              float* __restrict__ pooled,
                                              float* __restrict__ cnt, int N) {
    int t = threadIdx.x;
    int nstart = blockIdx.x * 256;
    if (nstart >= N) return;
    int nend = nstart + 256;
    if (nend > N) nend = N;
    float acc = 0.f;
    int cur = batch[nstart];
    int count = 0;
    for (int n = nstart; n < nend; ++n) {
        int g = batch[n];
        if (g != cur) {
            atomicAdd(&pooled[(size_t)cur * 128 + t], acc);
            if (t == 0) atomicAdd(&cnt[cur], (float)count);
            acc = 0.f;
            count = 0;
            cur = g;
        }
        acc += x2[(size_t)n * 128 + t];
        ++count;
    }
    atomicAdd(&pooled[(size_t)cur * 128 + t], acc);
    if (t == 0) atomicAdd(&cnt[cur], (float)count);
}

// ---------------- FC + log_softmax: one wave per graph ----------------
__global__ __launch_bounds__(64) void k_fc(const float* __restrict__ pooled,
                                           const float* __restrict__ cnt,
                                           const float* __restrict__ fcw,
                                           const float* __restrict__ fcb,
                                           float* __restrict__ out, int G) {
    int g = blockIdx.x;
    int c = threadIdx.x;  // 0..63, covers 2 features each
    float2 p = ((const float2*)pooled)[(size_t)g * 64 + c];
    float inv = 1.f / fmaxf(cnt[g], 1.f);
    p.x *= inv; p.y *= inv;
    float l[10];
#pragma unroll
    for (int j = 0; j < 10; ++j)
        l[j] = p.x * fcw[(2 * c) * 10 + j] + p.y * fcw[(2 * c + 1) * 10 + j];
#pragma unroll
    for (int j = 0; j < 10; ++j)
        for (int off = 1; off < 64; off <<= 1) l[j] += __shfl_xor(l[j], off);
    if (c == 0) {
        float lj[10];
        float m = -1e30f;
#pragma unroll
        for (int j = 0; j < 10; ++j) {
            lj[j] = l[j] + fcb[j];
            m = fmaxf(m, lj[j]);
        }
        float s = 0.f;
#pragma unroll
        for (int j = 0; j < 10; ++j) s += expf(lj[j] - m);
        float ls = logf(s);
#pragma unroll
        for (int j = 0; j < 10; ++j) out[(size_t)g * 10 + j] = lj[j] - m - ls;
    }
}

extern "C" void kernel_launch(void* const* d_in, const int* in_sizes, int n_in,
                              void* d_out, int out_size, void* d_ws, size_t ws_size,
                              hipStream_t stream) {
    const float* x     = (const float*)d_in[0];
    const int*   ei    = (const int*)d_in[1];
    const int*   batch = (const int*)d_in[2];
    const float* W1    = (const float*)d_in[3];
    const float* as1   = (const float*)d_in[4];
    const float* ad1   = (const float*)d_in[5];
    const float* b1    = (const float*)d_in[6];
    const float* W2    = (const float*)d_in[7];
    const float* as2   = (const float*)d_in[8];
    const float* ad2   = (const float*)d_in[9];
    const float* b2    = (const float*)d_in[10];
    const float* fcw   = (const float*)d_in[11];
    const float* fcb   = (const float*)d_in[12];
    float* out = (float*)d_out;

    const int N = in_sizes[0] / 128;
    const int E = in_sizes[1] / 2;
    const int G = out_size / 10;
    const int* srcp = ei;
    const int* dstp = ei + E;

    float* wf = (float*)d_ws;
    float* h1     = wf;                          // [N*64]
    float* x1pre  = wf + (size_t)N * 64;         // [N*64]
    float* x2     = wf;                          // alias of h1+x1pre (N*128), safe: h1/x1pre dead by then
    float* h2     = wf + (size_t)N * 128;        // [N*128]
    float* al1s_  = wf + (size_t)N * 256;        // [N*8]
    float* al1d_  = wf + (size_t)N * 264;        // [N*8]
    float* al2s_  = wf + (size_t)N * 272;        // [N]
    float* al2d_  = wf + (size_t)N * 273;        // [N]
    float* pooled = wf + (size_t)N * 274;        // [G*128]
    float* cnt    = pooled + (size_t)G * 128;    // [G]
    int* deg      = (int*)(cnt + G);             // [N]
    int* fill     = deg + N;                     // [N]
    int* row_ptr  = fill + N;                    // [N+1]
    int* col      = row_ptr + N + 1;             // [E+N]
    int* bsums    = col + (size_t)E + N;         // [<=512]

    // zero pooled, cnt, deg, fill in one shot (contiguous)
    size_t zbytes = ((size_t)G * 128 + G + 2 * (size_t)N) * sizeof(float);
    hipMemsetAsync(pooled, 0, zbytes, stream);

    const int nb64 = (N + 63) / 64;
    const int nb4  = (N + 3) / 4;
    const int nbS  = (N + 255) / 256;  // must be <= 512 for k_scan2 (N <= 131072)

    k_gemm1<<<nb64, 256, 0, stream>>>(x, W1, h1, N);
    k_al1<<<nb4, 256, 0, stream>>>(h1, as1, ad1, al1s_, al1d_, N);
    k_deg<<<(E + 255) / 256, 256, 0, stream>>>(dstp, deg, E);
    k_scan1<<<nbS, 256, 0, stream>>>(deg, row_ptr, bsums, N);
    k_scan2<<<1, 512, 0, stream>>>(bsums, nbS);
    k_scan3<<<nbS, 256, 0, stream>>>(row_ptr, bsums, N, E + N);
    k_fill<<<(E + N + 255) / 256, 256, 0, stream>>>(srcp, dstp, row_ptr, fill, col, E, N);
    k_edge1<<<nb4, 256, 0, stream>>>(h1, al1s_, al1d_, row_ptr, col, x1pre, N);
    k_gemm2<<<nb64, 256, 0, stream>>>(x1pre, W2, b1, h2, N);
    k_al2<<<nb4, 256, 0, stream>>>(h2, as2, ad2, al2s_, al2d_, N);
    k_edge2<<<nb4, 256, 0, stream>>>(h2, al2s_, al2d_, row_ptr, col, b2, x2, N);
    k_pool<<<nbS, 128, 0, stream>>>(x2, batch, pooled, cnt, N);
    k_fc<<<G, 64, 0, stream>>>(pooled, cnt, fcw, fcb, out, G);
}

// Round 2
// 596.036 us; speedup vs baseline: 1.2941x; 1.2941x over previous
//
#include <hip/hip_runtime.h>
#include <math.h>

// ---- GEMM1: h1[N,64] = x[N,128] @ W1[128,64], fused al1s/al1d epilogue ----
__global__ __launch_bounds__(256) void k_gemm1(const float* __restrict__ x,
                                               const float* __restrict__ W1,
                                               const float* __restrict__ as1,
                                               const float* __restrict__ ad1,
                                               float* __restrict__ h1,
                                               float* __restrict__ al1s,
                                               float* __restrict__ al1d, int N) {
    __shared__ float sB[128 * 64];  // 32 KB, full W1
    __shared__ float sA[64 * 68];   // 64 rows x 64 k-cols, stride 68
    const int t = threadIdx.x;
    const int n0 = blockIdx.x * 64;
    {   // stage full W1 (2048 float4)
        const float4* w4 = (const float4*)W1;
        float4* s4 = (float4*)sB;
#pragma unroll
        for (int i = 0; i < 8; ++i) s4[t + i * 256] = w4[t + i * 256];
    }
    const int r0 = (t >> 3) * 2;
    const int c0 = (t & 7) * 8;   // head = t&7, channels c0..c0+7
    float acc0[8] = {0, 0, 0, 0, 0, 0, 0, 0};
    float acc1[8] = {0, 0, 0, 0, 0, 0, 0, 0};
    for (int kb = 0; kb < 2; ++kb) {
        __syncthreads();
#pragma unroll
        for (int i = 0; i < 4; ++i) {
            int idx = t + i * 256;
            int r = idx >> 4, kc = idx & 15;
            int n = n0 + r;
            float4 v = make_float4(0.f, 0.f, 0.f, 0.f);
            if (n < N) v = ((const float4*)x)[(size_t)n * 32 + kb * 16 + kc];
            *(float4*)&sA[r * 68 + kc * 4] = v;
        }
        __syncthreads();
        const float* bptr = &sB[kb * 64 * 64];
#pragma unroll 8
        for (int kk = 0; kk < 64; ++kk) {
            float a0 = sA[r0 * 68 + kk];
            float a1 = sA[(r0 + 1) * 68 + kk];
            const float* bp = &bptr[kk * 64 + c0];
            float4 b0 = *(const float4*)bp;
            float4 b1v = *(const float4*)(bp + 4);
            acc0[0] += a0 * b0.x; acc0[1] += a0 * b0.y; acc0[2] += a0 * b0.z; acc0[3] += a0 * b0.w;
            acc0[4] += a0 * b1v.x; acc0[5] += a0 * b1v.y; acc0[6] += a0 * b1v.z; acc0[7] += a0 * b1v.w;
            acc1[0] += a1 * b0.x; acc1[1] += a1 * b0.y; acc1[2] += a1 * b0.z; acc1[3] += a1 * b0.w;
            acc1[4] += a1 * b1v.x; acc1[5] += a1 * b1v.y; acc1[6] += a1 * b1v.z; acc1[7] += a1 * b1v.w;
        }
    }
    // epilogue: h1 store + per-head attention dot products (no cross-lane needed)
    float ps0 = 0.f, pd0 = 0.f, ps1 = 0.f, pd1 = 0.f;
#pragma unroll
    for (int i = 0; i < 8; ++i) {
        float ws = as1[c0 + i], wd = ad1[c0 + i];
        ps0 += acc0[i] * ws; pd0 += acc0[i] * wd;
        ps1 += acc1[i] * ws; pd1 += acc1[i] * wd;
    }
    int n = n0 + r0;
    int head = t & 7;
    if (n < N) {
        *(float4*)&h1[(size_t)n * 64 + c0] = make_float4(acc0[0], acc0[1], acc0[2], acc0[3]);
        *(float4*)&h1[(size_t)n * 64 + c0 + 4] = make_float4(acc0[4], acc0[5], acc0[6], acc0[7]);
        al1s[(size_t)n * 8 + head] = ps0;
        al1d[(size_t)n * 8 + head] = pd0;
    }
    if (n + 1 < N) {
        *(float4*)&h1[(size_t)(n + 1) * 64 + c0] = make_float4(acc1[0], acc1[1], acc1[2], acc1[3]);
        *(float4*)&h1[(size_t)(n + 1) * 64 + c0 + 4] = make_float4(acc1[4], acc1[5], acc1[6], acc1[7]);
        al1s[(size_t)(n + 1) * 8 + head] = ps1;
        al1d[(size_t)(n + 1) * 8 + head] = pd1;
    }
}

// ---- GEMM2: h2[N,128] = relu(x1pre+b1) @ W2[64,128], fused al2s/al2d ----
__global__ __launch_bounds__(256) void k_gemm2(const float* __restrict__ x1pre,
                                               const float* __restrict__ W2,
                                               const float* __restrict__ b1,
                                               const float* __restrict__ as2,
                                               const float* __restrict__ ad2,
                                               float* __restrict__ h2,
                                               float* __restrict__ al2s,
                                               float* __restrict__ al2d, int N) {
    __shared__ float sB[64 * 128];
    __shared__ float sA[64 * 68];
    const int t = threadIdx.x;
    const int n0 = blockIdx.x * 64;
    {
        const float4* w4 = (const float4*)W2;
        float4* s4 = (float4*)sB;
#pragma unroll
        for (int i = 0; i < 8; ++i) s4[t + i * 256] = w4[t + i * 256];
    }
#pragma unroll
    for (int i = 0; i < 4; ++i) {
        int idx = t + i * 256;
        int r = idx >> 4, kc = idx & 15;
        int n = n0 + r;
        float4 v = make_float4(0.f, 0.f, 0.f, 0.f);
        if (n < N) {
            v = ((const float4*)x1pre)[(size_t)n * 16 + kc];
            float4 bb = ((const float4*)b1)[kc];
            v.x = fmaxf(v.x + bb.x, 0.f);
            v.y = fmaxf(v.y + bb.y, 0.f);
            v.z = fmaxf(v.z + bb.z, 0.f);
            v.w = fmaxf(v.w + bb.w, 0.f);
        }
        *(float4*)&sA[r * 68 + kc * 4] = v;
    }
    __syncthreads();
    const int r0 = (t >> 3) * 2;
    const int cb = (t & 7) * 4;  // cols: cb + 32*j + i
    float acc0[16], acc1[16];
#pragma unroll
    for (int i = 0; i < 16; ++i) { acc0[i] = 0.f; acc1[i] = 0.f; }
#pragma unroll 4
    for (int k = 0; k < 64; ++k) {
        float a0 = sA[r0 * 68 + k];
        float a1 = sA[(r0 + 1) * 68 + k];
#pragma unroll
        for (int j = 0; j < 4; ++j) {
            float4 b = *(const float4*)&sB[k * 128 + cb + 32 * j];
            acc0[j * 4 + 0] += a0 * b.x; acc0[j * 4 + 1] += a0 * b.y;
            acc0[j * 4 + 2] += a0 * b.z; acc0[j * 4 + 3] += a0 * b.w;
            acc1[j * 4 + 0] += a1 * b.x; acc1[j * 4 + 1] += a1 * b.y;
            acc1[j * 4 + 2] += a1 * b.z; acc1[j * 4 + 3] += a1 * b.w;
        }
    }
    // fused al2: partial dot over this thread's 16 cols, reduce across 8-lane group
    float ps0 = 0.f, pd0 = 0.f, ps1 = 0.f, pd1 = 0.f;
#pragma unroll
    for (int j = 0; j < 4; ++j)
#pragma unroll
        for (int i = 0; i < 4; ++i) {
            int cc = cb + 32 * j + i;
            float ws = as2[cc], wd = ad2[cc];
            ps0 += acc0[j * 4 + i] * ws; pd0 += acc0[j * 4 + i] * wd;
            ps1 += acc1[j * 4 + i] * ws; pd1 += acc1[j * 4 + i] * wd;
        }
#pragma unroll
    for (int off = 1; off < 8; off <<= 1) {
        ps0 += __shfl_xor(ps0, off); pd0 += __shfl_xor(pd0, off);
        ps1 += __shfl_xor(ps1, off); pd1 += __shfl_xor(pd1, off);
    }
    int n = n0 + r0;
    if (n < N) {
#pragma unroll
        for (int j = 0; j < 4; ++j)
            *(float4*)&h2[(size_t)n * 128 + cb + 32 * j] =
                make_float4(acc0[j * 4 + 0], acc0[j * 4 + 1], acc0[j * 4 + 2], acc0[j * 4 + 3]);
        if ((t & 7) == 0) { al2s[n] = ps0; al2d[n] = pd0; }
    }
    if (n + 1 < N) {
#pragma unroll
        for (int j = 0; j < 4; ++j)
            *(float4*)&h2[(size_t)(n + 1) * 128 + cb + 32 * j] =
                make_float4(acc1[j * 4 + 0], acc1[j * 4 + 1], acc1[j * 4 + 2], acc1[j * 4 + 3]);
        if ((t & 7) == 0) { al2s[n + 1] = ps1; al2d[n + 1] = pd1; }
    }
}

// ---------------- CSR construction ----------------
__global__ void k_deg(const int* __restrict__ dst, int* __restrict__ deg, int E) {
    int e = blockIdx.x * 256 + threadIdx.x;
    if (e < E) atomicAdd(&deg[dst[e]], 1);
}

__global__ void k_scan1(const int* __restrict__ deg, int* __restrict__ row_ptr,
                        int* __restrict__ bsums, int N) {
    __shared__ int sh[256];
    int t = threadIdx.x, b = blockIdx.x;
    int i = b * 256 + t;
    int v = (i < N) ? (deg[i] + 1) : 0;  // +1 for self-loop
    sh[t] = v;
    __syncthreads();
    int accv = v;
    for (int off = 1; off < 256; off <<= 1) {
        int u = (t >= off) ? sh[t - off] : 0;
        __syncthreads();
        accv += u;
        sh[t] = accv;
        __syncthreads();
    }
    if (i < N) row_ptr[i] = accv - v;
    if (t == 255) bsums[b] = accv;
}

__global__ void k_scan2(int* __restrict__ bsums, int nb) {
    __shared__ int sh[512];
    int t = threadIdx.x;
    int v = (t < nb) ? bsums[t] : 0;
    sh[t] = v;
    __syncthreads();
    int accv = v;
    for (int off = 1; off < 512; off <<= 1) {
        int u = (t >= off) ? sh[t - off] : 0;
        __syncthreads();
        accv += u;
        sh[t] = accv;
        __syncthreads();
    }
    if (t < nb) bsums[t] = accv - v;
}

__global__ void k_scan3(int* __restrict__ row_ptr, const int* __restrict__ bsums,
                        int N, int total) {
    int i = blockIdx.x * 256 + threadIdx.x;
    if (i < N) row_ptr[i] += bsums[blockIdx.x];
    if (i == 0) row_ptr[N] = total;
}

__global__ void k_fill(const int* __restrict__ src, const int* __restrict__ dst,
                       const int* __restrict__ row_ptr, int* __restrict__ fill,
                       int* __restrict__ col, int E, int N) {
    int i = blockIdx.x * 256 + threadIdx.x;
    if (i < E) {
        int d = dst[i];
        int pos = row_ptr[d] + atomicAdd(&fill[d], 1);
        col[pos] = src[i];
    } else if (i < E + N) {
        int n = i - E;
        int pos = row_ptr[n] + atomicAdd(&fill[n], 1);
        col[pos] = n;
    }
}

// ---- edge aggregation, layer 1: wave per dst node, unroll x4 ----
__global__ __launch_bounds__(256) void k_edge1(const float* __restrict__ h1,
                                               const float* __restrict__ al1s,
                                               const float* __restrict__ al1d,
                                               const int* __restrict__ row_ptr,
                                               const int* __restrict__ col,
                                               float* __restrict__ x1pre, int N) {
    int node = blockIdx.x * 4 + (threadIdx.x >> 6);
    if (node >= N) return;
    int c = threadIdx.x & 63;
    int h = c >> 3;
    float a_d = al1d[(size_t)node * 8 + h];
    int s0 = row_ptr[node], s1 = row_ptr[node + 1];
    float den = 0.f, acc = 0.f;
    int s = s0;
    for (; s + 4 <= s1; s += 4) {
        int i0 = col[s], i1 = col[s + 1], i2 = col[s + 2], i3 = col[s + 3];
        float e0 = al1s[(size_t)i0 * 8 + h];
        float e1 = al1s[(size_t)i1 * 8 + h];
        float e2 = al1s[(size_t)i2 * 8 + h];
        float e3 = al1s[(size_t)i3 * 8 + h];
        float v0 = h1[(size_t)i0 * 64 + c];
        float v1 = h1[(size_t)i1 * 64 + c];
        float v2 = h1[(size_t)i2 * 64 + c];
        float v3 = h1[(size_t)i3 * 64 + c];
        e0 += a_d; e1 += a_d; e2 += a_d; e3 += a_d;
        e0 = e0 > 0.f ? e0 : 0.2f * e0;
        e1 = e1 > 0.f ? e1 : 0.2f * e1;
        e2 = e2 > 0.f ? e2 : 0.2f * e2;
        e3 = e3 > 0.f ? e3 : 0.2f * e3;
        float w0 = __expf(e0), w1 = __expf(e1), w2 = __expf(e2), w3 = __expf(e3);
        den += (w0 + w1) + (w2 + w3);
        acc += w0 * v0 + w1 * v1 + w2 * v2 + w3 * v3;
    }
    for (; s < s1; ++s) {
        int i0 = col[s];
        float e0 = al1s[(size_t)i0 * 8 + h] + a_d;
        e0 = e0 > 0.f ? e0 : 0.2f * e0;
        float w0 = __expf(e0);
        den += w0;
        acc += w0 * h1[(size_t)i0 * 64 + c];
    }
    x1pre[(size_t)node * 64 + c] = acc / den;
}

// ---- edge aggregation, layer 2: wave per dst node, lane-parallel weights ----
__global__ __launch_bounds__(256) void k_edge2(const float* __restrict__ h2,
                                               const float* __restrict__ al2s,
                                               const float* __restrict__ al2d,
                                               const int* __restrict__ row_ptr,
                                               const int* __restrict__ col,
                                               const float* __restrict__ b2,
                                               float* __restrict__ x2, int N) {
    int node = blockIdx.x * 4 + (threadIdx.x >> 6);
    if (node >= N) return;
    int c = threadIdx.x & 63;
    float a_d = al2d[node];
    int s0 = row_ptr[node], s1 = row_ptr[node + 1];
    float accx = 0.f, accy = 0.f, den = 0.f;
    const float2* h22 = (const float2*)h2;
    for (int base = s0; base < s1; base += 64) {
        int idx = base + c;
        int cidx = idx < s1 ? idx : s1 - 1;
        int my_col = col[cidx];                   // one lane-parallel load / 64 edges
        float my_e = al2s[my_col] + a_d;          // one lane-parallel gather
        my_e = my_e > 0.f ? my_e : 0.2f * my_e;
        float my_w = (idx < s1) ? __expf(my_e) : 0.f;
        den += my_w;                              // lane-partial; wave-reduced later
        int cnt = s1 - base; if (cnt > 64) cnt = 64;
        int i = 0;
        for (; i + 4 <= cnt; i += 4) {
            int sA = __shfl(my_col, i),     sB = __shfl(my_col, i + 1);
            int sC = __shfl(my_col, i + 2), sD = __shfl(my_col, i + 3);
            float wA = __shfl(my_w, i),     wB = __shfl(my_w, i + 1);
            float wC = __shfl(my_w, i + 2), wD = __shfl(my_w, i + 3);
            float2 hA = h22[(size_t)sA * 64 + c];
            float2 hB = h22[(size_t)sB * 64 + c];
            float2 hC = h22[(size_t)sC * 64 + c];
            float2 hD = h22[(size_t)sD * 64 + c];
            accx += wA * hA.x; accy += wA * hA.y;
            accx += wB * hB.x; accy += wB * hB.y;
            accx += wC * hC.x; accy += wC * hC.y;
            accx += wD * hD.x; accy += wD * hD.y;
        }
        for (; i < cnt; ++i) {
            int sA = __shfl(my_col, i);
            float wA = __shfl(my_w, i);
            float2 hA = h22[(size_t)sA * 64 + c];
            accx += wA * hA.x; accy += wA * hA.y;
        }
    }
#pragma unroll
    for (int off = 1; off < 64; off <<= 1) den += __shfl_xor(den, off);
    float invd = 1.f / den;
    float2 ob = ((const float2*)b2)[c];
    float2 r;
    r.x = accx * invd + ob.x;
    r.y = accy * invd + ob.y;
    ((float2*)x2)[(size_t)node * 64 + c] = r;
}

// ---- mean pool over sorted batch (run-length chunked atomics) ----
__global__ __launch_bounds__(128) void k_pool(const float* __restrict__ x2,
                                              const int* __restrict__ batch,
                                              float* __restrict__ pooled,
                                              float* __restrict__ cnt, int N) {
    int t = threadIdx.x;
    int nstart = blockIdx.x * 128;
    if (nstart >= N) return;
    int nend = nstart + 128;
    if (nend > N) nend = N;
    float acc = 0.f;
    int cur = batch[nstart];
    int count = 0;
    for (int n = nstart; n < nend; ++n) {
        int g = batch[n];
        if (g != cur) {
            atomicAdd(&pooled[(size_t)cur * 128 + t], acc);
            if (t == 0) atomicAdd(&cnt[cur], (float)count);
            acc = 0.f;
            count = 0;
            cur = g;
        }
        acc += x2[(size_t)n * 128 + t];
        ++count;
    }
    atomicAdd(&pooled[(size_t)cur * 128 + t], acc);
    if (t == 0) atomicAdd(&cnt[cur], (float)count);
}

// ---- FC + log_softmax: one wave per graph ----
__global__ __launch_bounds__(64) void k_fc(const float* __restrict__ pooled,
                                           const float* __restrict__ cnt,
                                           const float* __restrict__ fcw,
                                           const float* __restrict__ fcb,
                                           float* __restrict__ out, int G) {
    int g = blockIdx.x;
    int c = threadIdx.x;
    float2 p = ((const float2*)pooled)[(size_t)g * 64 + c];
    float inv = 1.f / fmaxf(cnt[g], 1.f);
    p.x *= inv; p.y *= inv;
    float l[10];
#pragma unroll
    for (int j = 0; j < 10; ++j)
        l[j] = p.x * fcw[(2 * c) * 10 + j] + p.y * fcw[(2 * c + 1) * 10 + j];
#pragma unroll
    for (int j = 0; j < 10; ++j)
        for (int off = 1; off < 64; off <<= 1) l[j] += __shfl_xor(l[j], off);
    if (c == 0) {
        float lj[10];
        float m = -1e30f;
#pragma unroll
        for (int j = 0; j < 10; ++j) {
            lj[j] = l[j] + fcb[j];
            m = fmaxf(m, lj[j]);
        }
        float s = 0.f;
#pragma unroll
        for (int j = 0; j < 10; ++j) s += expf(lj[j] - m);
        float ls = logf(s);
#pragma unroll
        for (int j = 0; j < 10; ++j) out[(size_t)g * 10 + j] = lj[j] - m - ls;
    }
}

extern "C" void kernel_launch(void* const* d_in, const int* in_sizes, int n_in,
                              void* d_out, int out_size, void* d_ws, size_t ws_size,
                              hipStream_t stream) {
    const float* x     = (const float*)d_in[0];
    const int*   ei    = (const int*)d_in[1];
    const int*   batch = (const int*)d_in[2];
    const float* W1    = (const float*)d_in[3];
    const float* as1   = (const float*)d_in[4];
    const float* ad1   = (const float*)d_in[5];
    const float* b1    = (const float*)d_in[6];
    const float* W2    = (const float*)d_in[7];
    const float* as2   = (const float*)d_in[8];
    const float* ad2   = (const float*)d_in[9];
    const float* b2    = (const float*)d_in[10];
    const float* fcw   = (const float*)d_in[11];
    const float* fcb   = (const float*)d_in[12];
    float* out = (float*)d_out;

    const int N = in_sizes[0] / 128;
    const int E = in_sizes[1] / 2;
    const int G = out_size / 10;
    const int* srcp = ei;
    const int* dstp = ei + E;

    float* wf = (float*)d_ws;
    float* h1     = wf;                          // [N*64]
    float* x1pre  = wf + (size_t)N * 64;         // [N*64]
    float* x2     = wf;                          // alias (h1/x1pre dead by then)
    float* h2     = wf + (size_t)N * 128;        // [N*128]
    float* al1s_  = wf + (size_t)N * 256;        // [N*8]
    float* al1d_  = wf + (size_t)N * 264;        // [N*8]
    float* al2s_  = wf + (size_t)N * 272;        // [N]
    float* al2d_  = wf + (size_t)N * 273;        // [N]
    float* pooled = wf + (size_t)N * 274;        // [G*128]
    float* cnt    = pooled + (size_t)G * 128;    // [G]
    int* deg      = (int*)(cnt + G);             // [N]
    int* fill     = deg + N;                     // [N]
    int* row_ptr  = fill + N;                    // [N+1]
    int* col      = row_ptr + N + 1;             // [E+N]
    int* bsums    = col + (size_t)E + N;         // [<=512]

    size_t zbytes = ((size_t)G * 128 + G + 2 * (size_t)N) * sizeof(float);
    hipMemsetAsync(pooled, 0, zbytes, stream);

    const int nb64 = (N + 63) / 64;
    const int nb4  = (N + 3) / 4;
    const int nbS  = (N + 255) / 256;  // <= 512 for k_scan2
    const int nbP  = (N + 127) / 128;

    k_gemm1<<<nb64, 256, 0, stream>>>(x, W1, as1, ad1, h1, al1s_, al1d_, N);
    k_deg<<<(E + 255) / 256, 256, 0, stream>>>(dstp, deg, E);
    k_scan1<<<nbS, 256, 0, stream>>>(deg, row_ptr, bsums, N);
    k_scan2<<<1, 512, 0, stream>>>(bsums, nbS);
    k_scan3<<<nbS, 256, 0, stream>>>(row_ptr, bsums, N, E + N);
    k_fill<<<(E + N + 255) / 256, 256, 0, stream>>>(srcp, dstp, row_ptr, fill, col, E, N);
    k_edge1<<<nb4, 256, 0, stream>>>(h1, al1s_, al1d_, row_ptr, col, x1pre, N);
    k_gemm2<<<nb64, 256, 0, stream>>>(x1pre, W2, b1, as2, ad2, h2, al2s_, al2d_, N);
    k_edge2<<<nb4, 256, 0, stream>>>(h2, al2s_, al2d_, row_ptr, col, b2, x2, N);
    k_pool<<<nbP, 128, 0, stream>>>(x2, batch, pooled, cnt, N);
    k_fc<<<G, 64, 0, stream>>>(pooled, cnt, fcw, fcb, out, G);
}

// Round 3
// 542.647 us; speedup vs baseline: 1.4214x; 1.0984x over previous
//
#include <hip/hip_runtime.h>
#include <math.h>

typedef unsigned int uint;
typedef unsigned short ushort;

__device__ inline ushort f2bf(float f) {
    uint u = __float_as_uint(f);
    u += 0x7FFF + ((u >> 16) & 1);  // round-to-nearest-even
    return (ushort)(u >> 16);
}
__device__ inline float bf2f(ushort s) {
    return __uint_as_float(((uint)s) << 16);
}

// ---- GEMM1: h1b[N,64](bf16) = x[N,128] @ W1[128,64], fused al1s/al1d ----
__global__ __launch_bounds__(256) void k_gemm1(const float* __restrict__ x,
                                               const float* __restrict__ W1,
                                               const float* __restrict__ as1,
                                               const float* __restrict__ ad1,
                                               ushort* __restrict__ h1b,
                                               float* __restrict__ al1s,
                                               float* __restrict__ al1d, int N) {
    __shared__ float sB[128 * 64];
    __shared__ float sA[64 * 68];
    const int t = threadIdx.x;
    const int n0 = blockIdx.x * 64;
    {
        const float4* w4 = (const float4*)W1;
        float4* s4 = (float4*)sB;
#pragma unroll
        for (int i = 0; i < 8; ++i) s4[t + i * 256] = w4[t + i * 256];
    }
    const int r0 = (t >> 3) * 2;
    const int c0 = (t & 7) * 8;   // head = t&7, channels c0..c0+7
    float acc0[8] = {0, 0, 0, 0, 0, 0, 0, 0};
    float acc1[8] = {0, 0, 0, 0, 0, 0, 0, 0};
    for (int kb = 0; kb < 2; ++kb) {
        __syncthreads();
#pragma unroll
        for (int i = 0; i < 4; ++i) {
            int idx = t + i * 256;
            int r = idx >> 4, kc = idx & 15;
            int n = n0 + r;
            float4 v = make_float4(0.f, 0.f, 0.f, 0.f);
            if (n < N) v = ((const float4*)x)[(size_t)n * 32 + kb * 16 + kc];
            *(float4*)&sA[r * 68 + kc * 4] = v;
        }
        __syncthreads();
        const float* bptr = &sB[kb * 64 * 64];
#pragma unroll 8
        for (int kk = 0; kk < 64; ++kk) {
            float a0 = sA[r0 * 68 + kk];
            float a1 = sA[(r0 + 1) * 68 + kk];
            const float* bp = &bptr[kk * 64 + c0];
            float4 b0 = *(const float4*)bp;
            float4 b1v = *(const float4*)(bp + 4);
            acc0[0] += a0 * b0.x; acc0[1] += a0 * b0.y; acc0[2] += a0 * b0.z; acc0[3] += a0 * b0.w;
            acc0[4] += a0 * b1v.x; acc0[5] += a0 * b1v.y; acc0[6] += a0 * b1v.z; acc0[7] += a0 * b1v.w;
            acc1[0] += a1 * b0.x; acc1[1] += a1 * b0.y; acc1[2] += a1 * b0.z; acc1[3] += a1 * b0.w;
            acc1[4] += a1 * b1v.x; acc1[5] += a1 * b1v.y; acc1[6] += a1 * b1v.z; acc1[7] += a1 * b1v.w;
        }
    }
    float ps0 = 0.f, pd0 = 0.f, ps1 = 0.f, pd1 = 0.f;
#pragma unroll
    for (int i = 0; i < 8; ++i) {
        float ws = as1[c0 + i], wd = ad1[c0 + i];
        ps0 += acc0[i] * ws; pd0 += acc0[i] * wd;
        ps1 += acc1[i] * ws; pd1 += acc1[i] * wd;
    }
    int n = n0 + r0;
    int head = t & 7;
    if (n < N) {
        uint4 p;
        p.x = (uint)f2bf(acc0[0]) | ((uint)f2bf(acc0[1]) << 16);
        p.y = (uint)f2bf(acc0[2]) | ((uint)f2bf(acc0[3]) << 16);
        p.z = (uint)f2bf(acc0[4]) | ((uint)f2bf(acc0[5]) << 16);
        p.w = (uint)f2bf(acc0[6]) | ((uint)f2bf(acc0[7]) << 16);
        *(uint4*)&h1b[(size_t)n * 64 + c0] = p;
        al1s[(size_t)n * 8 + head] = ps0;
        al1d[(size_t)n * 8 + head] = pd0;
    }
    if (n + 1 < N) {
        uint4 p;
        p.x = (uint)f2bf(acc1[0]) | ((uint)f2bf(acc1[1]) << 16);
        p.y = (uint)f2bf(acc1[2]) | ((uint)f2bf(acc1[3]) << 16);
        p.z = (uint)f2bf(acc1[4]) | ((uint)f2bf(acc1[5]) << 16);
        p.w = (uint)f2bf(acc1[6]) | ((uint)f2bf(acc1[7]) << 16);
        *(uint4*)&h1b[(size_t)(n + 1) * 64 + c0] = p;
        al1s[(size_t)(n + 1) * 8 + head] = ps1;
        al1d[(size_t)(n + 1) * 8 + head] = pd1;
    }
}

// ---- GEMM2: h2b[N,128](bf16) = relu(x1pre+b1) @ W2[64,128], fused al2 ----
__global__ __launch_bounds__(256) void k_gemm2(const float* __restrict__ x1pre,
                                               const float* __restrict__ W2,
                                               const float* __restrict__ b1,
                                               const float* __restrict__ as2,
                                               const float* __restrict__ ad2,
                                               ushort* __restrict__ h2b,
                                               float* __restrict__ al2s,
                                               float* __restrict__ al2d, int N) {
    __shared__ float sB[64 * 128];
    __shared__ float sA[64 * 68];
    const int t = threadIdx.x;
    const int n0 = blockIdx.x * 64;
    {
        const float4* w4 = (const float4*)W2;
        float4* s4 = (float4*)sB;
#pragma unroll
        for (int i = 0; i < 8; ++i) s4[t + i * 256] = w4[t + i * 256];
    }
#pragma unroll
    for (int i = 0; i < 4; ++i) {
        int idx = t + i * 256;
        int r = idx >> 4, kc = idx & 15;
        int n = n0 + r;
        float4 v = make_float4(0.f, 0.f, 0.f, 0.f);
        if (n < N) {
            v = ((const float4*)x1pre)[(size_t)n * 16 + kc];
            float4 bb = ((const float4*)b1)[kc];
            v.x = fmaxf(v.x + bb.x, 0.f);
            v.y = fmaxf(v.y + bb.y, 0.f);
            v.z = fmaxf(v.z + bb.z, 0.f);
            v.w = fmaxf(v.w + bb.w, 0.f);
        }
        *(float4*)&sA[r * 68 + kc * 4] = v;
    }
    __syncthreads();
    const int r0 = (t >> 3) * 2;
    const int cb = (t & 7) * 4;
    float acc0[16], acc1[16];
#pragma unroll
    for (int i = 0; i < 16; ++i) { acc0[i] = 0.f; acc1[i] = 0.f; }
#pragma unroll 4
    for (int k = 0; k < 64; ++k) {
        float a0 = sA[r0 * 68 + k];
        float a1 = sA[(r0 + 1) * 68 + k];
#pragma unroll
        for (int j = 0; j < 4; ++j) {
            float4 b = *(const float4*)&sB[k * 128 + cb + 32 * j];
            acc0[j * 4 + 0] += a0 * b.x; acc0[j * 4 + 1] += a0 * b.y;
            acc0[j * 4 + 2] += a0 * b.z; acc0[j * 4 + 3] += a0 * b.w;
            acc1[j * 4 + 0] += a1 * b.x; acc1[j * 4 + 1] += a1 * b.y;
            acc1[j * 4 + 2] += a1 * b.z; acc1[j * 4 + 3] += a1 * b.w;
        }
    }
    float ps0 = 0.f, pd0 = 0.f, ps1 = 0.f, pd1 = 0.f;
#pragma unroll
    for (int j = 0; j < 4; ++j)
#pragma unroll
        for (int i = 0; i < 4; ++i) {
            int cc = cb + 32 * j + i;
            float ws = as2[cc], wd = ad2[cc];
            ps0 += acc0[j * 4 + i] * ws; pd0 += acc0[j * 4 + i] * wd;
            ps1 += acc1[j * 4 + i] * ws; pd1 += acc1[j * 4 + i] * wd;
        }
#pragma unroll
    for (int off = 1; off < 8; off <<= 1) {
        ps0 += __shfl_xor(ps0, off); pd0 += __shfl_xor(pd0, off);
        ps1 += __shfl_xor(ps1, off); pd1 += __shfl_xor(pd1, off);
    }
    int n = n0 + r0;
    if (n < N) {
#pragma unroll
        for (int j = 0; j < 4; ++j) {
            uint2 q;
            q.x = (uint)f2bf(acc0[j * 4 + 0]) | ((uint)f2bf(acc0[j * 4 + 1]) << 16);
            q.y = (uint)f2bf(acc0[j * 4 + 2]) | ((uint)f2bf(acc0[j * 4 + 3]) << 16);
            *(uint2*)&h2b[(size_t)n * 128 + cb + 32 * j] = q;
        }
        if ((t & 7) == 0) { al2s[n] = ps0; al2d[n] = pd0; }
    }
    if (n + 1 < N) {
#pragma unroll
        for (int j = 0; j < 4; ++j) {
            uint2 q;
            q.x = (uint)f2bf(acc1[j * 4 + 0]) | ((uint)f2bf(acc1[j * 4 + 1]) << 16);
            q.y = (uint)f2bf(acc1[j * 4 + 2]) | ((uint)f2bf(acc1[j * 4 + 3]) << 16);
            *(uint2*)&h2b[(size_t)(n + 1) * 128 + cb + 32 * j] = q;
        }
        if ((t & 7) == 0) { al2s[n + 1] = ps1; al2d[n + 1] = pd1; }
    }
}

// ---------------- CSR construction ----------------
__global__ void k_deg(const int* __restrict__ dst, int* __restrict__ deg, int E) {
    int e = blockIdx.x * 256 + threadIdx.x;
    if (e < E) atomicAdd(&deg[dst[e]], 1);
}

__global__ void k_scan1(const int* __restrict__ deg, int* __restrict__ row_ptr,
                        int* __restrict__ bsums, int N) {
    __shared__ int sh[256];
    int t = threadIdx.x, b = blockIdx.x;
    int i = b * 256 + t;
    int v = (i < N) ? (deg[i] + 1) : 0;  // +1 for self-loop
    sh[t] = v;
    __syncthreads();
    int accv = v;
    for (int off = 1; off < 256; off <<= 1) {
        int u = (t >= off) ? sh[t - off] : 0;
        __syncthreads();
        accv += u;
        sh[t] = accv;
        __syncthreads();
    }
    if (i < N) row_ptr[i] = accv - v;
    if (t == 255) bsums[b] = accv;
}

__global__ void k_scan2(int* __restrict__ bsums, int nb) {
    __shared__ int sh[512];
    int t = threadIdx.x;
    int v = (t < nb) ? bsums[t] : 0;
    sh[t] = v;
    __syncthreads();
    int accv = v;
    for (int off = 1; off < 512; off <<= 1) {
        int u = (t >= off) ? sh[t - off] : 0;
        __syncthreads();
        accv += u;
        sh[t] = accv;
        __syncthreads();
    }
    if (t < nb) bsums[t] = accv - v;
}

__global__ void k_scan3(int* __restrict__ row_ptr, const int* __restrict__ bsums,
                        int N, int total) {
    int i = blockIdx.x * 256 + threadIdx.x;
    if (i < N) row_ptr[i] += bsums[blockIdx.x];
    if (i == 0) row_ptr[N] = total;
}

__global__ void k_fill(const int* __restrict__ src, const int* __restrict__ dst,
                       const int* __restrict__ row_ptr, int* __restrict__ fill,
                       int* __restrict__ col, int E, int N) {
    int i = blockIdx.x * 256 + threadIdx.x;
    if (i < E) {
        int d = dst[i];
        int pos = row_ptr[d] + atomicAdd(&fill[d], 1);
        col[pos] = src[i];
    } else if (i < E + N) {
        int n = i - E;
        int pos = row_ptr[n] + atomicAdd(&fill[n], 1);
        col[pos] = n;
    }
}

// ---- edge aggregation, layer 1: wave per dst node, bf16 gather, unroll x8 ----
__global__ __launch_bounds__(256) void k_edge1(const ushort* __restrict__ h1b,
                                               const float* __restrict__ al1s,
                                               const float* __restrict__ al1d,
                                               const int* __restrict__ row_ptr,
                                               const int* __restrict__ col,
                                               float* __restrict__ x1pre, int N) {
    int node = blockIdx.x * 4 + (threadIdx.x >> 6);
    if (node >= N) return;
    int c = threadIdx.x & 63;
    int h = c >> 3;
    float a_d = al1d[(size_t)node * 8 + h];
    int s0 = row_ptr[node], s1 = row_ptr[node + 1];
    float den = 0.f, acc = 0.f;
    int s = s0;
    for (; s + 8 <= s1; s += 8) {
        int ii[8];
        float ee[8], vv[8];
#pragma unroll
        for (int u = 0; u < 8; ++u) ii[u] = col[s + u];
#pragma unroll
        for (int u = 0; u < 8; ++u) ee[u] = al1s[(size_t)ii[u] * 8 + h];
#pragma unroll
        for (int u = 0; u < 8; ++u) vv[u] = bf2f(h1b[(size_t)ii[u] * 64 + c]);
#pragma unroll
        for (int u = 0; u < 8; ++u) {
            float e = ee[u] + a_d;
            e = e > 0.f ? e : 0.2f * e;
            float w = __expf(e);
            den += w;
            acc += w * vv[u];
        }
    }
    for (; s < s1; ++s) {
        int i0 = col[s];
        float e0 = al1s[(size_t)i0 * 8 + h] + a_d;
        e0 = e0 > 0.f ? e0 : 0.2f * e0;
        float w0 = __expf(e0);
        den += w0;
        acc += w0 * bf2f(h1b[(size_t)i0 * 64 + c]);
    }
    x1pre[(size_t)node * 64 + c] = acc / den;
}

// ---- edge aggregation, layer 2: wave per node, bf16x2 gather, unroll x8 ----
__global__ __launch_bounds__(256) void k_edge2(const ushort* __restrict__ h2b,
                                               const float* __restrict__ al2s,
                                               const float* __restrict__ al2d,
                                               const int* __restrict__ row_ptr,
                                               const int* __restrict__ col,
                                               const float* __restrict__ b2,
                                               float* __restrict__ x2, int N) {
    int node = blockIdx.x * 4 + (threadIdx.x >> 6);
    if (node >= N) return;
    int c = threadIdx.x & 63;
    float a_d = al2d[node];
    int s0 = row_ptr[node], s1 = row_ptr[node + 1];
    float accx = 0.f, accy = 0.f, den = 0.f;
    const uint* h2u = (const uint*)h2b;  // 64 uints (bf16x2) per row
    for (int base = s0; base < s1; base += 64) {
        int idx = base + c;
        int cidx = idx < s1 ? idx : s1 - 1;
        int my_col = col[cidx];
        float my_e = al2s[my_col] + a_d;
        my_e = my_e > 0.f ? my_e : 0.2f * my_e;
        float my_w = (idx < s1) ? __expf(my_e) : 0.f;
        den += my_w;
        int cnt = s1 - base; if (cnt > 64) cnt = 64;
        int i = 0;
        for (; i + 8 <= cnt; i += 8) {
            int sc[8];
            float wc[8];
            uint uv[8];
#pragma unroll
            for (int u = 0; u < 8; ++u) { sc[u] = __shfl(my_col, i + u); wc[u] = __shfl(my_w, i + u); }
#pragma unroll
            for (int u = 0; u < 8; ++u) uv[u] = h2u[(size_t)sc[u] * 64 + c];
#pragma unroll
            for (int u = 0; u < 8; ++u) {
                float hx = __uint_as_float(uv[u] << 16);
                float hy = __uint_as_float(uv[u] & 0xFFFF0000u);
                accx += wc[u] * hx;
                accy += wc[u] * hy;
            }
        }
        for (; i < cnt; ++i) {
            int sA = __shfl(my_col, i);
            float wA = __shfl(my_w, i);
            uint uv = h2u[(size_t)sA * 64 + c];
            accx += wA * __uint_as_float(uv << 16);
            accy += wA * __uint_as_float(uv & 0xFFFF0000u);
        }
    }
#pragma unroll
    for (int off = 1; off < 64; off <<= 1) den += __shfl_xor(den, off);
    float invd = 1.f / den;
    float2 ob = ((const float2*)b2)[c];
    float2 r;
    r.x = accx * invd + ob.x;
    r.y = accy * invd + ob.y;
    ((float2*)x2)[(size_t)node * 64 + c] = r;
}

// ---- mean pool over sorted batch (run-length chunked atomics) ----
__global__ __launch_bounds__(128) void k_pool(const float* __restrict__ x2,
                                              const int* __restrict__ batch,
                                              float* __restrict__ pooled,
                                              float* __restrict__ cnt, int N) {
    int t = threadIdx.x;
    int nstart = blockIdx.x * 128;
    if (nstart >= N) return;
    int nend = nstart + 128;
    if (nend > N) nend = N;
    float acc = 0.f;
    int cur = batch[nstart];
    int count = 0;
    for (int n = nstart; n < nend; ++n) {
        int g = batch[n];
        if (g != cur) {
            atomicAdd(&pooled[(size_t)cur * 128 + t], acc);
            if (t == 0) atomicAdd(&cnt[cur], (float)count);
            acc = 0.f;
            count = 0;
            cur = g;
        }
        acc += x2[(size_t)n * 128 + t];
        ++count;
    }
    atomicAdd(&pooled[(size_t)cur * 128 + t], acc);
    if (t == 0) atomicAdd(&cnt[cur], (float)count);
}

// ---- FC + log_softmax: one wave per graph ----
__global__ __launch_bounds__(64) void k_fc(const float* __restrict__ pooled,
                                           const float* __restrict__ cnt,
                                           const float* __restrict__ fcw,
                                           const float* __restrict__ fcb,
                                           float* __restrict__ out, int G) {
    int g = blockIdx.x;
    int c = threadIdx.x;
    float2 p = ((const float2*)pooled)[(size_t)g * 64 + c];
    float inv = 1.f / fmaxf(cnt[g], 1.f);
    p.x *= inv; p.y *= inv;
    float l[10];
#pragma unroll
    for (int j = 0; j < 10; ++j)
        l[j] = p.x * fcw[(2 * c) * 10 + j] + p.y * fcw[(2 * c + 1) * 10 + j];
#pragma unroll
    for (int j = 0; j < 10; ++j)
        for (int off = 1; off < 64; off <<= 1) l[j] += __shfl_xor(l[j], off);
    if (c == 0) {
        float lj[10];
        float m = -1e30f;
#pragma unroll
        for (int j = 0; j < 10; ++j) {
            lj[j] = l[j] + fcb[j];
            m = fmaxf(m, lj[j]);
        }
        float s = 0.f;
#pragma unroll
        for (int j = 0; j < 10; ++j) s += expf(lj[j] - m);
        float ls = logf(s);
#pragma unroll
        for (int j = 0; j < 10; ++j) out[(size_t)g * 10 + j] = lj[j] - m - ls;
    }
}

extern "C" void kernel_launch(void* const* d_in, const int* in_sizes, int n_in,
                              void* d_out, int out_size, void* d_ws, size_t ws_size,
                              hipStream_t stream) {
    const float* x     = (const float*)d_in[0];
    const int*   ei    = (const int*)d_in[1];
    const int*   batch = (const int*)d_in[2];
    const float* W1    = (const float*)d_in[3];
    const float* as1   = (const float*)d_in[4];
    const float* ad1   = (const float*)d_in[5];
    const float* b1    = (const float*)d_in[6];
    const float* W2    = (const float*)d_in[7];
    const float* as2   = (const float*)d_in[8];
    const float* ad2   = (const float*)d_in[9];
    const float* b2    = (const float*)d_in[10];
    const float* fcw   = (const float*)d_in[11];
    const float* fcb   = (const float*)d_in[12];
    float* out = (float*)d_out;

    const int N = in_sizes[0] / 128;
    const int E = in_sizes[1] / 2;
    const int G = out_size / 10;
    const int* srcp = ei;
    const int* dstp = ei + E;

    // workspace layout (float units):
    //   [0,32N)      h1b (ushort N*64)          -- dead after k_edge1
    //   [32N,96N)    x1pre (f32 N*64)           -- dead after k_gemm2
    //   [0,128N)     x2 (f32 N*128)             -- written in k_edge2 (aliases dead h1b/x1pre)
    //   [128N,192N)  h2b (ushort N*128)
    //   [192N,200N)  al1s   [200N,208N) al1d
    //   [208N,209N)  al2s   [209N,210N) al2d
    //   [210N,...)   pooled[G*128], cnt[G], then int region
    float* wf = (float*)d_ws;
    ushort* h1b   = (ushort*)wf;
    float* x1pre  = wf + (size_t)N * 32;
    float* x2     = wf;
    ushort* h2b   = (ushort*)(wf + (size_t)N * 128);
    float* al1s_  = wf + (size_t)N * 192;
    float* al1d_  = wf + (size_t)N * 200;
    float* al2s_  = wf + (size_t)N * 208;
    float* al2d_  = wf + (size_t)N * 209;
    float* pooled = wf + (size_t)N * 210;
    float* cnt    = pooled + (size_t)G * 128;
    int* deg      = (int*)(cnt + G);
    int* fill     = deg + N;
    int* row_ptr  = fill + N;
    int* col      = row_ptr + N + 1;
    int* bsums    = col + (size_t)E + N;

    size_t zbytes = ((size_t)G * 128 + G + 2 * (size_t)N) * sizeof(float);
    hipMemsetAsync(pooled, 0, zbytes, stream);

    const int nb64 = (N + 63) / 64;
    const int nb4  = (N + 3) / 4;
    const int nbS  = (N + 255) / 256;  // <= 512 for k_scan2
    const int nbP  = (N + 127) / 128;

    k_gemm1<<<nb64, 256, 0, stream>>>(x, W1, as1, ad1, h1b, al1s_, al1d_, N);
    k_deg<<<(E + 255) / 256, 256, 0, stream>>>(dstp, deg, E);
    k_scan1<<<nbS, 256, 0, stream>>>(deg, row_ptr, bsums, N);
    k_scan2<<<1, 512, 0, stream>>>(bsums, nbS);
    k_scan3<<<nbS, 256, 0, stream>>>(row_ptr, bsums, N, E + N);
    k_fill<<<(E + N + 255) / 256, 256, 0, stream>>>(srcp, dstp, row_ptr, fill, col, E, N);
    k_edge1<<<nb4, 256, 0, stream>>>(h1b, al1s_, al1d_, row_ptr, col, x1pre, N);
    k_gemm2<<<nb64, 256, 0, stream>>>(x1pre, W2, b1, as2, ad2, h2b, al2s_, al2d_, N);
    k_edge2<<<nb4, 256, 0, stream>>>(h2b, al2s_, al2d_, row_ptr, col, b2, x2, N);
    k_pool<<<nbP, 128, 0, stream>>>(x2, batch, pooled, cnt, N);
    k_fc<<<G, 64, 0, stream>>>(pooled, cnt, fcw, fcb, out, G);
}

// Round 4
// 461.812 us; speedup vs baseline: 1.6702x; 1.1750x over previous
//
#include <hip/hip_runtime.h>
#include <math.h>

typedef unsigned int uint;
typedef unsigned short ushort;

__device__ inline ushort f2bf(float f) {
    uint u = __float_as_uint(f);
    u += 0x7FFF + ((u >> 16) & 1);  // round-to-nearest-even
    return (ushort)(u >> 16);
}
__device__ inline float bf2f(ushort s) {
    return __uint_as_float(((uint)s) << 16);
}

// ---- GEMM1: h1b[N,64](bf16) = x[N,128] @ W1[128,64], fused al1s/al1d ----
__global__ __launch_bounds__(256) void k_gemm1(const float* __restrict__ x,
                                               const float* __restrict__ W1,
                                               const float* __restrict__ as1,
                                               const float* __restrict__ ad1,
                                               ushort* __restrict__ h1b,
                                               float* __restrict__ al1s,
                                               float* __restrict__ al1d, int N) {
    __shared__ float sB[128 * 64];
    __shared__ float sA[64 * 68];
    const int t = threadIdx.x;
    const int n0 = blockIdx.x * 64;
    {
        const float4* w4 = (const float4*)W1;
        float4* s4 = (float4*)sB;
#pragma unroll
        for (int i = 0; i < 8; ++i) s4[t + i * 256] = w4[t + i * 256];
    }
    const int r0 = (t >> 3) * 2;
    const int c0 = (t & 7) * 8;   // head = t&7, channels c0..c0+7
    float acc0[8] = {0, 0, 0, 0, 0, 0, 0, 0};
    float acc1[8] = {0, 0, 0, 0, 0, 0, 0, 0};
    for (int kb = 0; kb < 2; ++kb) {
        __syncthreads();
#pragma unroll
        for (int i = 0; i < 4; ++i) {
            int idx = t + i * 256;
            int r = idx >> 4, kc = idx & 15;
            int n = n0 + r;
            float4 v = make_float4(0.f, 0.f, 0.f, 0.f);
            if (n < N) v = ((const float4*)x)[(size_t)n * 32 + kb * 16 + kc];
            *(float4*)&sA[r * 68 + kc * 4] = v;
        }
        __syncthreads();
        const float* bptr = &sB[kb * 64 * 64];
#pragma unroll 8
        for (int kk = 0; kk < 64; ++kk) {
            float a0 = sA[r0 * 68 + kk];
            float a1 = sA[(r0 + 1) * 68 + kk];
            const float* bp = &bptr[kk * 64 + c0];
            float4 b0 = *(const float4*)bp;
            float4 b1v = *(const float4*)(bp + 4);
            acc0[0] += a0 * b0.x; acc0[1] += a0 * b0.y; acc0[2] += a0 * b0.z; acc0[3] += a0 * b0.w;
            acc0[4] += a0 * b1v.x; acc0[5] += a0 * b1v.y; acc0[6] += a0 * b1v.z; acc0[7] += a0 * b1v.w;
            acc1[0] += a1 * b0.x; acc1[1] += a1 * b0.y; acc1[2] += a1 * b0.z; acc1[3] += a1 * b0.w;
            acc1[4] += a1 * b1v.x; acc1[5] += a1 * b1v.y; acc1[6] += a1 * b1v.z; acc1[7] += a1 * b1v.w;
        }
    }
    float ps0 = 0.f, pd0 = 0.f, ps1 = 0.f, pd1 = 0.f;
#pragma unroll
    for (int i = 0; i < 8; ++i) {
        float ws = as1[c0 + i], wd = ad1[c0 + i];
        ps0 += acc0[i] * ws; pd0 += acc0[i] * wd;
        ps1 += acc1[i] * ws; pd1 += acc1[i] * wd;
    }
    int n = n0 + r0;
    int head = t & 7;
    if (n < N) {
        uint4 p;
        p.x = (uint)f2bf(acc0[0]) | ((uint)f2bf(acc0[1]) << 16);
        p.y = (uint)f2bf(acc0[2]) | ((uint)f2bf(acc0[3]) << 16);
        p.z = (uint)f2bf(acc0[4]) | ((uint)f2bf(acc0[5]) << 16);
        p.w = (uint)f2bf(acc0[6]) | ((uint)f2bf(acc0[7]) << 16);
        *(uint4*)&h1b[(size_t)n * 64 + c0] = p;
        al1s[(size_t)n * 8 + head] = ps0;
        al1d[(size_t)n * 8 + head] = pd0;
    }
    if (n + 1 < N) {
        uint4 p;
        p.x = (uint)f2bf(acc1[0]) | ((uint)f2bf(acc1[1]) << 16);
        p.y = (uint)f2bf(acc1[2]) | ((uint)f2bf(acc1[3]) << 16);
        p.z = (uint)f2bf(acc1[4]) | ((uint)f2bf(acc1[5]) << 16);
        p.w = (uint)f2bf(acc1[6]) | ((uint)f2bf(acc1[7]) << 16);
        *(uint4*)&h1b[(size_t)(n + 1) * 64 + c0] = p;
        al1s[(size_t)(n + 1) * 8 + head] = ps1;
        al1d[(size_t)(n + 1) * 8 + head] = pd1;
    }
}

// ---- GEMM2: h2b[N,128](bf16) = relu(x1pre+b1) @ W2[64,128], fused al2 ----
__global__ __launch_bounds__(256) void k_gemm2(const float* __restrict__ x1pre,
                                               const float* __restrict__ W2,
                                               const float* __restrict__ b1,
                                               const float* __restrict__ as2,
                                               const float* __restrict__ ad2,
                                               ushort* __restrict__ h2b,
                                               float* __restrict__ al2s,
                                               float* __restrict__ al2d, int N) {
    __shared__ float sB[64 * 128];
    __shared__ float sA[64 * 68];
    const int t = threadIdx.x;
    const int n0 = blockIdx.x * 64;
    {
        const float4* w4 = (const float4*)W2;
        float4* s4 = (float4*)sB;
#pragma unroll
        for (int i = 0; i < 8; ++i) s4[t + i * 256] = w4[t + i * 256];
    }
#pragma unroll
    for (int i = 0; i < 4; ++i) {
        int idx = t + i * 256;
        int r = idx >> 4, kc = idx & 15;
        int n = n0 + r;
        float4 v = make_float4(0.f, 0.f, 0.f, 0.f);
        if (n < N) {
            v = ((const float4*)x1pre)[(size_t)n * 16 + kc];
            float4 bb = ((const float4*)b1)[kc];
            v.x = fmaxf(v.x + bb.x, 0.f);
            v.y = fmaxf(v.y + bb.y, 0.f);
            v.z = fmaxf(v.z + bb.z, 0.f);
            v.w = fmaxf(v.w + bb.w, 0.f);
        }
        *(float4*)&sA[r * 68 + kc * 4] = v;
    }
    __syncthreads();
    const int r0 = (t >> 3) * 2;
    const int cb = (t & 7) * 4;
    float acc0[16], acc1[16];
#pragma unroll
    for (int i = 0; i < 16; ++i) { acc0[i] = 0.f; acc1[i] = 0.f; }
#pragma unroll 4
    for (int k = 0; k < 64; ++k) {
        float a0 = sA[r0 * 68 + k];
        float a1 = sA[(r0 + 1) * 68 + k];
#pragma unroll
        for (int j = 0; j < 4; ++j) {
            float4 b = *(const float4*)&sB[k * 128 + cb + 32 * j];
            acc0[j * 4 + 0] += a0 * b.x; acc0[j * 4 + 1] += a0 * b.y;
            acc0[j * 4 + 2] += a0 * b.z; acc0[j * 4 + 3] += a0 * b.w;
            acc1[j * 4 + 0] += a1 * b.x; acc1[j * 4 + 1] += a1 * b.y;
            acc1[j * 4 + 2] += a1 * b.z; acc1[j * 4 + 3] += a1 * b.w;
        }
    }
    float ps0 = 0.f, pd0 = 0.f, ps1 = 0.f, pd1 = 0.f;
#pragma unroll
    for (int j = 0; j < 4; ++j)
#pragma unroll
        for (int i = 0; i < 4; ++i) {
            int cc = cb + 32 * j + i;
            float ws = as2[cc], wd = ad2[cc];
            ps0 += acc0[j * 4 + i] * ws; pd0 += acc0[j * 4 + i] * wd;
            ps1 += acc1[j * 4 + i] * ws; pd1 += acc1[j * 4 + i] * wd;
        }
#pragma unroll
    for (int off = 1; off < 8; off <<= 1) {
        ps0 += __shfl_xor(ps0, off); pd0 += __shfl_xor(pd0, off);
        ps1 += __shfl_xor(ps1, off); pd1 += __shfl_xor(pd1, off);
    }
    int n = n0 + r0;
    if (n < N) {
#pragma unroll
        for (int j = 0; j < 4; ++j) {
            uint2 q;
            q.x = (uint)f2bf(acc0[j * 4 + 0]) | ((uint)f2bf(acc0[j * 4 + 1]) << 16);
            q.y = (uint)f2bf(acc0[j * 4 + 2]) | ((uint)f2bf(acc0[j * 4 + 3]) << 16);
            *(uint2*)&h2b[(size_t)n * 128 + cb + 32 * j] = q;
        }
        if ((t & 7) == 0) { al2s[n] = ps0; al2d[n] = pd0; }
    }
    if (n + 1 < N) {
#pragma unroll
        for (int j = 0; j < 4; ++j) {
            uint2 q;
            q.x = (uint)f2bf(acc1[j * 4 + 0]) | ((uint)f2bf(acc1[j * 4 + 1]) << 16);
            q.y = (uint)f2bf(acc1[j * 4 + 2]) | ((uint)f2bf(acc1[j * 4 + 3]) << 16);
            *(uint2*)&h2b[(size_t)(n + 1) * 128 + cb + 32 * j] = q;
        }
        if ((t & 7) == 0) { al2s[n + 1] = ps1; al2d[n + 1] = pd1; }
    }
}

// ---------------- CSR construction ----------------
// pass 1: histogram + rank (atomic return stored coalesced, x4 ILP)
__global__ __launch_bounds__(256) void k_deg(const int* __restrict__ dst,
                                             int* __restrict__ deg,
                                             int* __restrict__ rank, int E) {
    int base = (blockIdx.x * 256 + threadIdx.x) * 4;
    if (base + 4 <= E) {
        int4 d = *(const int4*)&dst[base];
        int r0 = atomicAdd(&deg[d.x], 1);
        int r1 = atomicAdd(&deg[d.y], 1);
        int r2 = atomicAdd(&deg[d.z], 1);
        int r3 = atomicAdd(&deg[d.w], 1);
        *(int4*)&rank[base] = make_int4(r0, r1, r2, r3);
    } else {
        for (int e = base; e < E; ++e) {
            int d = dst[e];
            rank[e] = atomicAdd(&deg[d], 1);
        }
    }
}

__global__ void k_scan1(const int* __restrict__ deg, int* __restrict__ row_ptr,
                        int* __restrict__ bsums, int N) {
    __shared__ int sh[256];
    int t = threadIdx.x, b = blockIdx.x;
    int i = b * 256 + t;
    int v = (i < N) ? (deg[i] + 1) : 0;  // +1 for self-loop
    sh[t] = v;
    __syncthreads();
    int accv = v;
    for (int off = 1; off < 256; off <<= 1) {
        int u = (t >= off) ? sh[t - off] : 0;
        __syncthreads();
        accv += u;
        sh[t] = accv;
        __syncthreads();
    }
    if (i < N) row_ptr[i] = accv - v;
    if (t == 255) bsums[b] = accv;
}

__global__ void k_scan2(int* __restrict__ bsums, int nb) {
    __shared__ int sh[512];
    int t = threadIdx.x;
    int v = (t < nb) ? bsums[t] : 0;
    sh[t] = v;
    __syncthreads();
    int accv = v;
    for (int off = 1; off < 512; off <<= 1) {
        int u = (t >= off) ? sh[t - off] : 0;
        __syncthreads();
        accv += u;
        sh[t] = accv;
        __syncthreads();
    }
    if (t < nb) bsums[t] = accv - v;
}

// pass 3: finalize row_ptr + write self-loops (monotone col slots)
__global__ void k_scan3(int* __restrict__ row_ptr, const int* __restrict__ bsums,
                        const int* __restrict__ deg, int* __restrict__ col,
                        int N, int total) {
    int i = blockIdx.x * 256 + threadIdx.x;
    if (i < N) {
        int rp = row_ptr[i] + bsums[blockIdx.x];
        row_ptr[i] = rp;
        col[rp + deg[i]] = i;  // self-loop at the end of row i
    }
    if (i == 0) row_ptr[N] = total;
}

// pass 4: atomic-free scatter fill (x4 ILP)
__global__ __launch_bounds__(256) void k_fill(const int* __restrict__ src,
                                              const int* __restrict__ dst,
                                              const int* __restrict__ rank,
                                              const int* __restrict__ row_ptr,
                                              int* __restrict__ col, int E) {
    int base = (blockIdx.x * 256 + threadIdx.x) * 4;
    if (base + 4 <= E) {
        int4 d = *(const int4*)&dst[base];
        int4 s = *(const int4*)&src[base];
        int4 r = *(const int4*)&rank[base];
        int p0 = row_ptr[d.x] + r.x;
        int p1 = row_ptr[d.y] + r.y;
        int p2 = row_ptr[d.z] + r.z;
        int p3 = row_ptr[d.w] + r.w;
        col[p0] = s.x;
        col[p1] = s.y;
        col[p2] = s.z;
        col[p3] = s.w;
    } else {
        for (int e = base; e < E; ++e) col[row_ptr[dst[e]] + rank[e]] = src[e];
    }
}

// ---- edge aggregation, layer 1: wave per dst node, bf16 gather, unroll x8 ----
__global__ __launch_bounds__(256) void k_edge1(const ushort* __restrict__ h1b,
                                               const float* __restrict__ al1s,
                                               const float* __restrict__ al1d,
                                               const int* __restrict__ row_ptr,
                                               const int* __restrict__ col,
                                               float* __restrict__ x1pre, int N) {
    int node = blockIdx.x * 4 + (threadIdx.x >> 6);
    if (node >= N) return;
    int c = threadIdx.x & 63;
    int h = c >> 3;
    float a_d = al1d[(size_t)node * 8 + h];
    int s0 = row_ptr[node], s1 = row_ptr[node + 1];
    float den = 0.f, acc = 0.f;
    int s = s0;
    for (; s + 8 <= s1; s += 8) {
        int ii[8];
        float ee[8], vv[8];
#pragma unroll
        for (int u = 0; u < 8; ++u) ii[u] = col[s + u];
#pragma unroll
        for (int u = 0; u < 8; ++u) ee[u] = al1s[(size_t)ii[u] * 8 + h];
#pragma unroll
        for (int u = 0; u < 8; ++u) vv[u] = bf2f(h1b[(size_t)ii[u] * 64 + c]);
#pragma unroll
        for (int u = 0; u < 8; ++u) {
            float e = ee[u] + a_d;
            e = e > 0.f ? e : 0.2f * e;
            float w = __expf(e);
            den += w;
            acc += w * vv[u];
        }
    }
    for (; s < s1; ++s) {
        int i0 = col[s];
        float e0 = al1s[(size_t)i0 * 8 + h] + a_d;
        e0 = e0 > 0.f ? e0 : 0.2f * e0;
        float w0 = __expf(e0);
        den += w0;
        acc += w0 * bf2f(h1b[(size_t)i0 * 64 + c]);
    }
    x1pre[(size_t)node * 64 + c] = acc / den;
}

// ---- edge aggregation, layer 2: wave per node, bf16x2 gather, unroll x8 ----
__global__ __launch_bounds__(256) void k_edge2(const ushort* __restrict__ h2b,
                                               const float* __restrict__ al2s,
                                               const float* __restrict__ al2d,
                                               const int* __restrict__ row_ptr,
                                               const int* __restrict__ col,
                                               const float* __restrict__ b2,
                                               float* __restrict__ x2, int N) {
    int node = blockIdx.x * 4 + (threadIdx.x >> 6);
    if (node >= N) return;
    int c = threadIdx.x & 63;
    float a_d = al2d[node];
    int s0 = row_ptr[node], s1 = row_ptr[node + 1];
    float accx = 0.f, accy = 0.f, den = 0.f;
    const uint* h2u = (const uint*)h2b;  // 64 uints (bf16x2) per row
    for (int base = s0; base < s1; base += 64) {
        int idx = base + c;
        int cidx = idx < s1 ? idx : s1 - 1;
        int my_col = col[cidx];
        float my_e = al2s[my_col] + a_d;
        my_e = my_e > 0.f ? my_e : 0.2f * my_e;
        float my_w = (idx < s1) ? __expf(my_e) : 0.f;
        den += my_w;
        int cnt = s1 - base; if (cnt > 64) cnt = 64;
        int i = 0;
        for (; i + 8 <= cnt; i += 8) {
            int sc[8];
            float wc[8];
            uint uv[8];
#pragma unroll
            for (int u = 0; u < 8; ++u) { sc[u] = __shfl(my_col, i + u); wc[u] = __shfl(my_w, i + u); }
#pragma unroll
            for (int u = 0; u < 8; ++u) uv[u] = h2u[(size_t)sc[u] * 64 + c];
#pragma unroll
            for (int u = 0; u < 8; ++u) {
                float hx = __uint_as_float(uv[u] << 16);
                float hy = __uint_as_float(uv[u] & 0xFFFF0000u);
                accx += wc[u] * hx;
                accy += wc[u] * hy;
            }
        }
        for (; i < cnt; ++i) {
            int sA = __shfl(my_col, i);
            float wA = __shfl(my_w, i);
            uint uv = h2u[(size_t)sA * 64 + c];
            accx += wA * __uint_as_float(uv << 16);
            accy += wA * __uint_as_float(uv & 0xFFFF0000u);
        }
    }
#pragma unroll
    for (int off = 1; off < 64; off <<= 1) den += __shfl_xor(den, off);
    float invd = 1.f / den;
    float2 ob = ((const float2*)b2)[c];
    float2 r;
    r.x = accx * invd + ob.x;
    r.y = accy * invd + ob.y;
    ((float2*)x2)[(size_t)node * 64 + c] = r;
}

// ---- mean pool over sorted batch (run-length chunked atomics) ----
__global__ __launch_bounds__(128) void k_pool(const float* __restrict__ x2,
                                              const int* __restrict__ batch,
                                              float* __restrict__ pooled,
                                              float* __restrict__ cnt, int N) {
    int t = threadIdx.x;
    int nstart = blockIdx.x * 128;
    if (nstart >= N) return;
    int nend = nstart + 128;
    if (nend > N) nend = N;
    float acc = 0.f;
    int cur = batch[nstart];
    int count = 0;
    for (int n = nstart; n < nend; ++n) {
        int g = batch[n];
        if (g != cur) {
            atomicAdd(&pooled[(size_t)cur * 128 + t], acc);
            if (t == 0) atomicAdd(&cnt[cur], (float)count);
            acc = 0.f;
            count = 0;
            cur = g;
        }
        acc += x2[(size_t)n * 128 + t];
        ++count;
    }
    atomicAdd(&pooled[(size_t)cur * 128 + t], acc);
    if (t == 0) atomicAdd(&cnt[cur], (float)count);
}

// ---- FC + log_softmax: one wave per graph ----
__global__ __launch_bounds__(64) void k_fc(const float* __restrict__ pooled,
                                           const float* __restrict__ cnt,
                                           const float* __restrict__ fcw,
                                           const float* __restrict__ fcb,
                                           float* __restrict__ out, int G) {
    int g = blockIdx.x;
    int c = threadIdx.x;
    float2 p = ((const float2*)pooled)[(size_t)g * 64 + c];
    float inv = 1.f / fmaxf(cnt[g], 1.f);
    p.x *= inv; p.y *= inv;
    float l[10];
#pragma unroll
    for (int j = 0; j < 10; ++j)
        l[j] = p.x * fcw[(2 * c) * 10 + j] + p.y * fcw[(2 * c + 1) * 10 + j];
#pragma unroll
    for (int j = 0; j < 10; ++j)
        for (int off = 1; off < 64; off <<= 1) l[j] += __shfl_xor(l[j], off);
    if (c == 0) {
        float lj[10];
        float m = -1e30f;
#pragma unroll
        for (int j = 0; j < 10; ++j) {
            lj[j] = l[j] + fcb[j];
            m = fmaxf(m, lj[j]);
        }
        float s = 0.f;
#pragma unroll
        for (int j = 0; j < 10; ++j) s += expf(lj[j] - m);
        float ls = logf(s);
#pragma unroll
        for (int j = 0; j < 10; ++j) out[(size_t)g * 10 + j] = lj[j] - m - ls;
    }
}

extern "C" void kernel_launch(void* const* d_in, const int* in_sizes, int n_in,
                              void* d_out, int out_size, void* d_ws, size_t ws_size,
                              hipStream_t stream) {
    const float* x     = (const float*)d_in[0];
    const int*   ei    = (const int*)d_in[1];
    const int*   batch = (const int*)d_in[2];
    const float* W1    = (const float*)d_in[3];
    const float* as1   = (const float*)d_in[4];
    const float* ad1   = (const float*)d_in[5];
    const float* b1    = (const float*)d_in[6];
    const float* W2    = (const float*)d_in[7];
    const float* as2   = (const float*)d_in[8];
    const float* ad2   = (const float*)d_in[9];
    const float* b2    = (const float*)d_in[10];
    const float* fcw   = (const float*)d_in[11];
    const float* fcb   = (const float*)d_in[12];
    float* out = (float*)d_out;

    const int N = in_sizes[0] / 128;
    const int E = in_sizes[1] / 2;
    const int G = out_size / 10;
    const int* srcp = ei;
    const int* dstp = ei + E;

    // workspace layout (float units):
    //   [0,32N)      h1b (ushort N*64)          -- dead after k_edge1
    //   [32N,96N)    x1pre (f32 N*64)           -- dead after k_gemm2
    //   [0,128N)     x2 (f32 N*128)             -- aliases dead h1b/x1pre
    //   [128N,192N)  h2b (ushort N*128)
    //   [192N,200N)  al1s   [200N,208N) al1d
    //   [208N,209N)  al2s   [209N,210N) al2d
    //   [210N,...)   pooled[G*128], cnt[G], then int region
    float* wf = (float*)d_ws;
    ushort* h1b   = (ushort*)wf;
    float* x1pre  = wf + (size_t)N * 32;
    float* x2     = wf;
    ushort* h2b   = (ushort*)(wf + (size_t)N * 128);
    float* al1s_  = wf + (size_t)N * 192;
    float* al1d_  = wf + (size_t)N * 200;
    float* al2s_  = wf + (size_t)N * 208;
    float* al2d_  = wf + (size_t)N * 209;
    float* pooled = wf + (size_t)N * 210;
    float* cnt    = pooled + (size_t)G * 128;
    int* deg      = (int*)(cnt + G);             // [N]
    int* row_ptr  = deg + N;                     // [N+1]
    int* col      = row_ptr + N + 1;             // [E+N]
    int* rank     = col + (size_t)E + N;         // [E]
    int* bsums    = rank + E;                    // [<=512]

    // zero pooled, cnt, deg (contiguous)
    size_t zbytes = ((size_t)G * 128 + G + (size_t)N) * sizeof(float);
    hipMemsetAsync(pooled, 0, zbytes, stream);

    const int nb64 = (N + 63) / 64;
    const int nb4  = (N + 3) / 4;
    const int nbS  = (N + 255) / 256;   // <= 512 for k_scan2
    const int nbP  = (N + 127) / 128;
    const int nbE4 = (E + 1023) / 1024; // 4 edges/thread

    k_deg<<<nbE4, 256, 0, stream>>>(dstp, deg, rank, E);
    k_gemm1<<<nb64, 256, 0, stream>>>(x, W1, as1, ad1, h1b, al1s_, al1d_, N);
    k_scan1<<<nbS, 256, 0, stream>>>(deg, row_ptr, bsums, N);
    k_scan2<<<1, 512, 0, stream>>>(bsums, nbS);
    k_scan3<<<nbS, 256, 0, stream>>>(row_ptr, bsums, deg, col, N, E + N);
    k_fill<<<nbE4, 256, 0, stream>>>(srcp, dstp, rank, row_ptr, col, E);
    k_edge1<<<nb4, 256, 0, stream>>>(h1b, al1s_, al1d_, row_ptr, col, x1pre, N);
    k_gemm2<<<nb64, 256, 0, stream>>>(x1pre, W2, b1, as2, ad2, h2b, al2s_, al2d_, N);
    k_edge2<<<nb4, 256, 0, stream>>>(h2b, al2s_, al2d_, row_ptr, col, b2, x2, N);
    k_pool<<<nbP, 128, 0, stream>>>(x2, batch, pooled, cnt, N);
    k_fc<<<G, 64, 0, stream>>>(pooled, cnt, fcw, fcb, out, G);
}